// Round 2
// baseline (556.716 us; speedup 1.0000x reference)
//
#include <hip/hip_runtime.h>

// HashDistill: per group k of 16 rows xS + 16 rows xT (D=256):
//   xx = (sum of all 32 rows)/32
//   row_i' = m_i*row_i + (1-m_i)*xx ; n_i = row_i'/||row_i'||
//   triu-sum of Gram(n) = (||sum_i n_i||^2 - 32)/2      (diag==1, symmetric)
// out = -sum_k (||s_k||^2 - 32) * 0.5 / (496 * 131072)
//
// Single fused kernel: last block (device-scope atomic counter) reduces ws.

#define NPOS 16
#define DDIM 256
#define NUMK 8192
#define BATCH 131072.0f
#define NPAIRS 496.0f

__global__ __launch_bounds__(256) void hk_fused_kernel(
    const float* __restrict__ xS,
    const float* __restrict__ xT,
    const float* __restrict__ pm,
    float* __restrict__ ws,
    int* __restrict__ counter,
    float* __restrict__ out)
{
    const int k    = blockIdx.x;
    const int tid  = threadIdx.x;
    const int wid  = tid >> 6;     // 0..3
    const int lane = tid & 63;

    // wave 0: xS rows 0-7, wave 1: xS rows 8-15, wave 2: xT rows 0-7, wave 3: xT rows 8-15
    const float* __restrict__ src = (wid < 2) ? xS : xT;
    const int rowBase  = k * NPOS + (wid & 1) * 8;
    const int maskBase = k * (2 * NPOS) + ((wid < 2) ? 0 : NPOS) + (wid & 1) * 8;

    // Each lane holds a float4 column slice (cols lane*4 .. lane*4+3) of 8 rows.
    const float4* __restrict__ p =
        reinterpret_cast<const float4*>(src + (size_t)rowBase * DDIM) + lane;
    float4 x[8];
#pragma unroll
    for (int r = 0; r < 8; ++r) x[r] = p[r * (DDIM / 4)];

    // Masks for this wave's 8 rows (issued early, broadcast loads)
    float m[8];
#pragma unroll
    for (int r = 0; r < 8; ++r) m[r] = pm[maskBase + r];

    // Partial column sums (this wave's 8 rows)
    float4 cs = x[0];
#pragma unroll
    for (int r = 1; r < 8; ++r) {
        cs.x += x[r].x; cs.y += x[r].y; cs.z += x[r].z; cs.w += x[r].w;
    }

    __shared__ float4 ldsA[4][64];
    __shared__ float4 ldsB[4][64];
    ldsA[wid][lane] = cs;
    __syncthreads();

    float4 xx;
    xx.x = (ldsA[0][lane].x + ldsA[1][lane].x + ldsA[2][lane].x + ldsA[3][lane].x) * (1.0f / 32.0f);
    xx.y = (ldsA[0][lane].y + ldsA[1][lane].y + ldsA[2][lane].y + ldsA[3][lane].y) * (1.0f / 32.0f);
    xx.z = (ldsA[0][lane].z + ldsA[1][lane].z + ldsA[2][lane].z + ldsA[3][lane].z) * (1.0f / 32.0f);
    xx.w = (ldsA[0][lane].w + ldsA[1][lane].w + ldsA[2][lane].w + ldsA[3][lane].w) * (1.0f / 32.0f);

    // Mix, normalize, accumulate normalized-row sum s (per-lane float4 slice)
    float4 s = make_float4(0.f, 0.f, 0.f, 0.f);
#pragma unroll
    for (int r = 0; r < 8; ++r) {
        const float om = 1.0f - m[r];
        float4 y;
        y.x = m[r] * x[r].x + om * xx.x;
        y.y = m[r] * x[r].y + om * xx.y;
        y.z = m[r] * x[r].z + om * xx.z;
        y.w = m[r] * x[r].w + om * xx.w;
        float ss = y.x * y.x + y.y * y.y + y.z * y.z + y.w * y.w;
#pragma unroll
        for (int off = 32; off; off >>= 1) ss += __shfl_xor(ss, off);
        const float rn = rsqrtf(ss);
        s.x += y.x * rn; s.y += y.y * rn; s.z += y.z * rn; s.w += y.w * rn;
    }

    ldsB[wid][lane] = s;
    __syncthreads();

    if (wid == 0) {
        float4 st;
        st.x = ldsB[0][lane].x + ldsB[1][lane].x + ldsB[2][lane].x + ldsB[3][lane].x;
        st.y = ldsB[0][lane].y + ldsB[1][lane].y + ldsB[2][lane].y + ldsB[3][lane].y;
        st.z = ldsB[0][lane].z + ldsB[1][lane].z + ldsB[2][lane].z + ldsB[3][lane].z;
        st.w = ldsB[0][lane].w + ldsB[1][lane].w + ldsB[2][lane].w + ldsB[3][lane].w;
        float d2 = st.x * st.x + st.y * st.y + st.z * st.z + st.w * st.w;
#pragma unroll
        for (int off = 32; off; off >>= 1) d2 += __shfl_xor(d2, off);
        if (lane == 0) {
            // device-visible store of this group's partial
            __hip_atomic_store(&ws[k], d2 - 32.0f, __ATOMIC_RELAXED,
                               __HIP_MEMORY_SCOPE_AGENT);
        }
    }

    // ---- last-block final reduction (deterministic fixed-order sum) ----
    __shared__ int lastFlag;
    if (tid == 0) {
        __threadfence();  // make ws[k] visible device-wide before counting
        int prev = __hip_atomic_fetch_add(counter, 1, __ATOMIC_ACQ_REL,
                                          __HIP_MEMORY_SCOPE_AGENT);
        lastFlag = (prev == NUMK - 1) ? 1 : 0;
    }
    __syncthreads();

    if (lastFlag) {
        __threadfence();  // acquire side
        float acc = 0.f;
#pragma unroll
        for (int i = 0; i < NUMK / 256; ++i) {
            acc += __hip_atomic_load(&ws[tid + i * 256], __ATOMIC_RELAXED,
                                     __HIP_MEMORY_SCOPE_AGENT);
        }
#pragma unroll
        for (int off = 32; off; off >>= 1) acc += __shfl_xor(acc, off);
        __shared__ float part[4];
        if (lane == 0) part[wid] = acc;
        __syncthreads();
        if (tid == 0) {
            float t = part[0] + part[1] + part[2] + part[3];
            *out = t * (-0.5f / (NPAIRS * BATCH));
        }
    }
}

extern "C" void kernel_launch(void* const* d_in, const int* in_sizes, int n_in,
                              void* d_out, int out_size, void* d_ws, size_t ws_size,
                              hipStream_t stream) {
    const float* xS = (const float*)d_in[0];
    const float* xT = (const float*)d_in[1];
    const float* pm = (const float*)d_in[2];
    float* ws      = (float*)d_ws;
    int*   counter = (int*)((char*)d_ws + NUMK * sizeof(float));
    float* out     = (float*)d_out;

    hipMemsetAsync(counter, 0, sizeof(int), stream);
    hk_fused_kernel<<<NUMK, 256, 0, stream>>>(xS, xT, pm, ws, counter, out);
}

// Round 3
// 47.025 us; speedup vs baseline: 11.8388x; 11.8388x over previous
//
#include <hip/hip_runtime.h>

// HashDistill: per group k of 16 rows xS + 16 rows xT (D=256):
//   xx = (sum of all 32 rows)/32
//   row_i' = m_i*row_i + (1-m_i)*xx ; n_i = row_i'/||row_i'||
//   triu-sum of Gram(n) = (||sum_i n_i||^2 - 32)/2      (diag==1, symmetric)
// out = -sum_k (||s_k||^2 - 32) * 0.5 / (496 * 131072)
//
// Two kernels: per-group partials (memory-bound streaming, ~43 us), then a
// single-block deterministic tree reduce. NOTE (R2 post-mortem): do NOT fuse
// via last-block-done — per-block agent-scope fences cost ~90 ns each on
// gfx950 (non-coherent per-XCD L2s) -> 700 us of overhead at 8192 blocks.

#define NPOS 16
#define DDIM 256
#define NUMK 8192
#define BATCH 131072.0f
#define NPAIRS 496.0f

__global__ __launch_bounds__(256) void hk_group_kernel(
    const float* __restrict__ xS,
    const float* __restrict__ xT,
    const float* __restrict__ pm,
    float* __restrict__ ws)
{
    const int k    = blockIdx.x;
    const int tid  = threadIdx.x;
    const int wid  = tid >> 6;     // 0..3
    const int lane = tid & 63;

    // wave 0: xS rows 0-7, wave 1: xS rows 8-15, wave 2: xT rows 0-7, wave 3: xT rows 8-15
    const float* __restrict__ src = (wid < 2) ? xS : xT;
    const int rowBase  = k * NPOS + (wid & 1) * 8;
    const int maskBase = k * (2 * NPOS) + ((wid < 2) ? 0 : NPOS) + (wid & 1) * 8;

    // Each lane holds a float4 column slice (cols lane*4 .. lane*4+3) of 8 rows.
    const float4* __restrict__ p =
        reinterpret_cast<const float4*>(src + (size_t)rowBase * DDIM) + lane;
    float4 x[8];
#pragma unroll
    for (int r = 0; r < 8; ++r) x[r] = p[r * (DDIM / 4)];

    // Masks for this wave's 8 rows (wave-uniform scalar loads, issued early)
    float m[8];
#pragma unroll
    for (int r = 0; r < 8; ++r) m[r] = pm[maskBase + r];

    // Partial column sums (this wave's 8 rows)
    float4 cs = x[0];
#pragma unroll
    for (int r = 1; r < 8; ++r) {
        cs.x += x[r].x; cs.y += x[r].y; cs.z += x[r].z; cs.w += x[r].w;
    }

    __shared__ float4 ldsA[4][64];
    __shared__ float4 ldsB[4][64];
    ldsA[wid][lane] = cs;
    __syncthreads();

    float4 xx;
    xx.x = (ldsA[0][lane].x + ldsA[1][lane].x + ldsA[2][lane].x + ldsA[3][lane].x) * (1.0f / 32.0f);
    xx.y = (ldsA[0][lane].y + ldsA[1][lane].y + ldsA[2][lane].y + ldsA[3][lane].y) * (1.0f / 32.0f);
    xx.z = (ldsA[0][lane].z + ldsA[1][lane].z + ldsA[2][lane].z + ldsA[3][lane].z) * (1.0f / 32.0f);
    xx.w = (ldsA[0][lane].w + ldsA[1][lane].w + ldsA[2][lane].w + ldsA[3][lane].w) * (1.0f / 32.0f);

    // Mix, normalize, accumulate normalized-row sum s (per-lane float4 slice)
    float4 s = make_float4(0.f, 0.f, 0.f, 0.f);
#pragma unroll
    for (int r = 0; r < 8; ++r) {
        const float om = 1.0f - m[r];
        float4 y;
        y.x = m[r] * x[r].x + om * xx.x;
        y.y = m[r] * x[r].y + om * xx.y;
        y.z = m[r] * x[r].z + om * xx.z;
        y.w = m[r] * x[r].w + om * xx.w;
        float ss = y.x * y.x + y.y * y.y + y.z * y.z + y.w * y.w;
#pragma unroll
        for (int off = 32; off; off >>= 1) ss += __shfl_xor(ss, off);
        const float rn = rsqrtf(ss);
        s.x += y.x * rn; s.y += y.y * rn; s.z += y.z * rn; s.w += y.w * rn;
    }

    ldsB[wid][lane] = s;
    __syncthreads();

    if (wid == 0) {
        float4 st;
        st.x = ldsB[0][lane].x + ldsB[1][lane].x + ldsB[2][lane].x + ldsB[3][lane].x;
        st.y = ldsB[0][lane].y + ldsB[1][lane].y + ldsB[2][lane].y + ldsB[3][lane].y;
        st.z = ldsB[0][lane].z + ldsB[1][lane].z + ldsB[2][lane].z + ldsB[3][lane].z;
        st.w = ldsB[0][lane].w + ldsB[1][lane].w + ldsB[2][lane].w + ldsB[3][lane].w;
        float d2 = st.x * st.x + st.y * st.y + st.z * st.z + st.w * st.w;
#pragma unroll
        for (int off = 32; off; off >>= 1) d2 += __shfl_xor(d2, off);
        if (lane == 0) ws[k] = d2 - 32.0f;   // (||s||^2 - trace); scaled in reduce
    }
}

__global__ __launch_bounds__(1024) void hk_reduce_kernel(
    const float* __restrict__ ws, float* __restrict__ out)
{
    const int tid = threadIdx.x;
    float s = 0.f;
#pragma unroll
    for (int i = 0; i < NUMK / 1024; ++i) s += ws[tid + i * 1024];
#pragma unroll
    for (int off = 32; off; off >>= 1) s += __shfl_xor(s, off);

    __shared__ float part[16];
    if ((tid & 63) == 0) part[tid >> 6] = s;
    __syncthreads();
    if (tid == 0) {
        float t = 0.f;
#pragma unroll
        for (int i = 0; i < 16; ++i) t += part[i];
        *out = t * (-0.5f / (NPAIRS * BATCH));
    }
}

extern "C" void kernel_launch(void* const* d_in, const int* in_sizes, int n_in,
                              void* d_out, int out_size, void* d_ws, size_t ws_size,
                              hipStream_t stream) {
    const float* xS = (const float*)d_in[0];
    const float* xT = (const float*)d_in[1];
    const float* pm = (const float*)d_in[2];
    float* ws  = (float*)d_ws;
    float* out = (float*)d_out;

    hk_group_kernel<<<NUMK, 256, 0, stream>>>(xS, xT, pm, ws);
    hk_reduce_kernel<<<1, 1024, 0, stream>>>(ws, out);
}